// Round 9
// baseline (2913.532 us; speedup 1.0000x reference)
//
#include <hip/hip_runtime.h>

#define TSTEPS 2000
#define NBATCH 16
#define DDIM   512
#define HDIM   512
#define MTOT   (NBATCH * TSTEPS)
#define LEPS   1e-5f

typedef _Float16 f16x8 __attribute__((ext_vector_type(8)));
typedef _Float16 f16x4 __attribute__((ext_vector_type(4)));
typedef _Float16 f16x2 __attribute__((ext_vector_type(2)));
typedef float    f32x4 __attribute__((ext_vector_type(4)));
typedef unsigned long long u64;

// ---------------- Phase 1: w = BN(x @ W^T), f16 MFMA ----------------  (r4, verified ~60us)
__global__ __launch_bounds__(256) void gemm_bn_f16_kernel(
    const float* __restrict__ x, const float* __restrict__ W,
    const float* __restrict__ gamma, const float* __restrict__ beta,
    const float* __restrict__ rmean, const float* __restrict__ rvar,
    float* __restrict__ out_a, float* __restrict__ out_z)
{
  __shared__ _Float16 Asm[128 * 64];
  __shared__ _Float16 Bsm[128 * 64];
  const int tid  = threadIdx.x;
  const int wv   = tid >> 6;
  const int lane = tid & 63;
  const int c    = lane & 15;
  const int hi   = lane >> 4;
  const int m0   = blockIdx.x * 128;
  const int n0   = blockIdx.y * 128;

  float invg[2], mng[2], btg[2];
#pragma unroll
  for (int nt = 0; nt < 2; ++nt) {
    const int gc = n0 + wv * 32 + nt * 16 + c;
    invg[nt] = gamma[gc] * rsqrtf(rvar[gc] + LEPS);
    mng[nt]  = rmean[gc];
    btg[nt]  = beta[gc];
  }

  f32x4 acc[8][2];
#pragma unroll
  for (int mt = 0; mt < 8; ++mt)
#pragma unroll
    for (int nt = 0; nt < 2; ++nt) acc[mt][nt] = (f32x4){0.f, 0.f, 0.f, 0.f};

  const int sf4  = tid & 15;
  const int srow = tid >> 4;

  for (int k0 = 0; k0 < DDIM; k0 += 64) {
    __syncthreads();
#pragma unroll
    for (int p = 0; p < 8; ++p) {
      const int r = p * 16 + srow;
      float4 va = *(const float4*)&x[(size_t)(m0 + r) * DDIM + k0 + sf4 * 4];
      float4 vb = *(const float4*)&W[(size_t)(n0 + r) * DDIM + k0 + sf4 * 4];
      f16x4 ha, hb;
      ha[0] = (_Float16)va.x; ha[1] = (_Float16)va.y;
      ha[2] = (_Float16)va.z; ha[3] = (_Float16)va.w;
      hb[0] = (_Float16)vb.x; hb[1] = (_Float16)vb.y;
      hb[2] = (_Float16)vb.z; hb[3] = (_Float16)vb.w;
      const int byo = r * 128 + ((sf4 * 8) ^ ((r & 7) << 4));
      *(f16x4*)((char*)Asm + byo) = ha;
      *(f16x4*)((char*)Bsm + byo) = hb;
    }
    __syncthreads();
#pragma unroll
    for (int kc = 0; kc < 2; ++kc) {
      const int kof = (kc * 32 + hi * 8) * 2;
      f16x8 bfr[2];
#pragma unroll
      for (int nt = 0; nt < 2; ++nt) {
        const int rr = wv * 32 + nt * 16 + c;
        bfr[nt] = *(const f16x8*)((const char*)Bsm + rr * 128 + (kof ^ ((rr & 7) << 4)));
      }
#pragma unroll
      for (int mt = 0; mt < 8; ++mt) {
        const int rr = mt * 16 + c;
        f16x8 afr = *(const f16x8*)((const char*)Asm + rr * 128 + (kof ^ ((rr & 7) << 4)));
        acc[mt][0] = __builtin_amdgcn_mfma_f32_16x16x32_f16(afr, bfr[0], acc[mt][0], 0, 0, 0);
        acc[mt][1] = __builtin_amdgcn_mfma_f32_16x16x32_f16(afr, bfr[1], acc[mt][1], 0, 0, 0);
      }
    }
  }

  const bool isA = (n0 < HDIM);
  float* dst = isA ? out_a : out_z;
  const int cb = isA ? n0 : (n0 - HDIM);
#pragma unroll
  for (int mt = 0; mt < 8; ++mt)
#pragma unroll
    for (int nt = 0; nt < 2; ++nt) {
      const int col = cb + wv * 32 + nt * 16 + c;
#pragma unroll
      for (int i = 0; i < 4; ++i) {
        const int row = m0 + mt * 16 + hi * 4 + i;
        dst[(size_t)row * HDIM + col] = (acc[mt][nt][i] - mng[nt]) * invg[nt] + btg[nt];
      }
    }
}

// ---------------- Phase 2: pre-activation publish, consumer-side gate math ----------
// 128 blocks = 16 batches x 8 groups (bid = g*16+b). Block publishes cols
// [g0,g0+64); wave w owns cols g0+w*8..+8 with lane c<8 = a-row, c>=8 = z-row
// (r5 mapping) so one __shfl_xor(gv,8) pairs a/z dots IN-WAVE.
// Per iteration t (0..TSTEPS inclusive):
//   A (consumer, all 512 thr, col=tid): spin on {tag=t, a_pre:f16, zg_pre:f16}
//      atom; gate math in f32; h state in PER-THREAD REGISTER (identical
//      across blocks: same atom inputs, same deterministic FP ops); write
//      f16 h -> hbuf[t&1] (parity dbuf closes the 1-barrier write/read race).
//   bar1 (the only barrier).
//   B (publisher): ring w pre-loads (hidden), 16 MFMAs in 4 indep chains,
//      shfl_xor(8), add w, v_cvt_pkrtz pack, publish ONE u64 per col right
//      after own wave's MFMA (~30cy pre-publish tail vs r7's ~300cy
//      gbuf+bar2+sigmoid path).
//   D (hidden tail): owner out-store of h_t (row t-1), ring write (carried
//      prefetch), issue w[t+4] load.
// Protocol: equality spin on parity slots; publish(t+1) is ordered after ALL
// block threads' spin(t) by bar1 -> no reader of tag t-1 exists when its slot
// is overwritten (r3 argument). memset tags each launch.
__global__ __launch_bounds__(512, 2) void rnn_sync_kernel(
    const float* __restrict__ U,
    float* __restrict__ out,              // [16][2000][512]: w_a in, h out (in place)
    const float* __restrict__ wz,         // [16][2000][512]
    u64* __restrict__ xbuf)               // [2][16][512] {tag, a:f16, zg:f16}
{
  __shared__ __align__(16) _Float16 hbuf[2][512];
  __shared__ float waring[8][64];
  __shared__ float wzring[8][64];

  const int tid  = threadIdx.x;
  const int w    = tid >> 6;
  const int lane = tid & 63;
  const int c    = lane & 15;
  const int hi   = lane >> 4;
  const int bid  = blockIdx.x;
  const int b    = bid & 15, g = bid >> 4;
  const int g0   = g * 64;
  const size_t obase = (size_t)b * TSTEPS * HDIM;

  // persistent U B-fragments (r5 mapping: in-wave a/z pairing)
  const int urow = (c < 8) ? (g0 + w * 8 + c) : (HDIM + g0 + w * 8 + (c - 8));
  f16x8 ufrag[16];
  {
    const float* up = &U[(size_t)urow * HDIM + hi * 8];
#pragma unroll
    for (int kt = 0; kt < 16; ++kt) {
      float4 lo = *(const float4*)&up[kt * 32];
      float4 h4 = *(const float4*)&up[kt * 32 + 4];
      f16x8 f;
      f[0] = (_Float16)lo.x; f[1] = (_Float16)lo.y;
      f[2] = (_Float16)lo.z; f[3] = (_Float16)lo.w;
      f[4] = (_Float16)h4.x; f[5] = (_Float16)h4.y;
      f[6] = (_Float16)h4.z; f[7] = (_Float16)h4.w;
      ufrag[kt] = f;
    }
  }

  hbuf[0][tid] = (_Float16)0.f;
  hbuf[1][tid] = (_Float16)0.f;
#pragma unroll
  for (int p = 0; p < 3; ++p) {
    if (tid < 64)        waring[p][tid]      = out[obase + (size_t)p * HDIM + g0 + tid];
    else if (tid < 128)  wzring[p][tid - 64] = wz [obase + (size_t)p * HDIM + g0 + (tid - 64)];
  }
  float pv_carry = 0.f;                       // holds w[t+3] entering iteration t
  if (tid < 64)       pv_carry = out[obase + (size_t)3 * HDIM + g0 + tid];
  else if (tid < 128) pv_carry = wz [obase + (size_t)3 * HDIM + g0 + (tid - 64)];

  float hreg = 0.f;                           // h[tid], f32, register-carried
  const bool ispub = (hi == 0) && (c < 8);
  const int  pcol  = g0 + w * 8 + c;          // published col (valid for c<8)
  const int  jloc  = w * 8 + c;               // ring index   (valid for c<8)
  const bool owner = (tid >> 6) == g;         // block owns col tid for out-store
  __syncthreads();

  for (int t = 0; t <= TSTEPS; ++t) {
    // ---- A: spin for tag t, consumer-side gate math, hbuf write ----
    if (t > 0) {
      const u64* xp = &xbuf[((size_t)(t & 1) * NBATCH + b) * HDIM + tid];
      u64 v;
      do {
        v = __hip_atomic_load(xp, __ATOMIC_RELAXED, __HIP_MEMORY_SCOPE_AGENT);
      } while ((unsigned)(v >> 32) != (unsigned)t);
      const f16x2 pk = __builtin_bit_cast(f16x2, (unsigned)v);
      const float a_pre = (float)pk[0];
      const float zgp   = (float)pk[1];
      const float z  = 1.f / (1.f + __expf(-zgp));
      const float hc = fmaxf(a_pre, 0.f);
      hreg = z * hreg + (1.f - z) * hc;        // h_t[tid]
      if (t < TSTEPS) hbuf[t & 1][tid] = (_Float16)hreg;
    }
    if (t == TSTEPS) {                         // epilogue: final out row only
      if (owner) out[obase + (size_t)(TSTEPS - 1) * HDIM + tid] = hreg;
      break;
    }
    __syncthreads();                           // bar1 (the only barrier)

    // ---- B: ring pre-loads (hidden under MFMA), gates, publish ----
    float wa_r = 0.f, wz_r = 0.f;
    if (ispub) {
      wa_r = waring[t & 7][jloc];
      wz_r = wzring[t & 7][jloc];
    }
    f32x4 acc0 = {0.f, 0.f, 0.f, 0.f};
    f32x4 acc1 = {0.f, 0.f, 0.f, 0.f};
    f32x4 acc2 = {0.f, 0.f, 0.f, 0.f};
    f32x4 acc3 = {0.f, 0.f, 0.f, 0.f};
    const _Float16* hb = hbuf[t & 1];
#pragma unroll
    for (int q = 0; q < 4; ++q) {
      f16x8 a0 = *(const f16x8*)&hb[(q * 4 + 0) * 32 + hi * 8];
      f16x8 a1 = *(const f16x8*)&hb[(q * 4 + 1) * 32 + hi * 8];
      f16x8 a2 = *(const f16x8*)&hb[(q * 4 + 2) * 32 + hi * 8];
      f16x8 a3 = *(const f16x8*)&hb[(q * 4 + 3) * 32 + hi * 8];
      acc0 = __builtin_amdgcn_mfma_f32_16x16x32_f16(a0, ufrag[q * 4 + 0], acc0, 0, 0, 0);
      acc1 = __builtin_amdgcn_mfma_f32_16x16x32_f16(a1, ufrag[q * 4 + 1], acc1, 0, 0, 0);
      acc2 = __builtin_amdgcn_mfma_f32_16x16x32_f16(a2, ufrag[q * 4 + 2], acc2, 0, 0, 0);
      acc3 = __builtin_amdgcn_mfma_f32_16x16x32_f16(a3, ufrag[q * 4 + 3], acc3, 0, 0, 0);
    }
    const float gv   = (acc0[0] + acc1[0]) + (acc2[0] + acc3[0]);  // own-row dot
    const float peer = __shfl_xor(gv, 8);                          // paired row dot
    if (ispub) {                                // ~30cy tail: add w, pack, publish
      const float a_pre  = gv   + wa_r;
      const float zg_pre = peer + wz_r;
      const unsigned bits =
          __builtin_bit_cast(unsigned, __builtin_amdgcn_cvt_pkrtz(a_pre, zg_pre));
      const u64 pkt = ((u64)(unsigned)(t + 1) << 32) | (u64)bits;
      __hip_atomic_store(&xbuf[((size_t)((t + 1) & 1) * NBATCH + b) * HDIM + pcol],
                         pkt, __ATOMIC_RELAXED, __HIP_MEMORY_SCOPE_AGENT);
    }

    // ---- D: hidden tail -- out-store, ring write (carry), issue w[t+4] ----
    if (owner && t >= 1) out[obase + (size_t)(t - 1) * HDIM + tid] = hreg;
    if (t + 3 < TSTEPS) {
      if (tid < 64)       waring[(t + 3) & 7][tid]      = pv_carry;
      else if (tid < 128) wzring[(t + 3) & 7][tid - 64] = pv_carry;
    }
    if (t + 4 < TSTEPS) {
      if (tid < 64)       pv_carry = out[obase + (size_t)(t + 4) * HDIM + g0 + tid];
      else if (tid < 128) pv_carry = wz [obase + (size_t)(t + 4) * HDIM + g0 + (tid - 64)];
    }
  }
}

extern "C" void kernel_launch(void* const* d_in, const int* in_sizes, int n_in,
                              void* d_out, int out_size, void* d_ws, size_t ws_size,
                              hipStream_t stream) {
  const float* x     = (const float*)d_in[0];
  const float* W     = (const float*)d_in[1];
  const float* U     = (const float*)d_in[2];
  const float* gamma = (const float*)d_in[3];
  const float* beta  = (const float*)d_in[4];
  const float* rmean = (const float*)d_in[5];
  const float* rvar  = (const float*)d_in[6];
  float* out = (float*)d_out;

  const size_t wz_bytes = (size_t)MTOT * HDIM * sizeof(float);   // 65,536,000
  float* wzp = (float*)d_ws;
  u64*  xbuf = (u64*)((char*)d_ws + wz_bytes);                   // [2][16][512] u64

  hipMemsetAsync(xbuf, 0, (size_t)2 * NBATCH * HDIM * sizeof(u64), stream);

  dim3 g1(MTOT / 128, (HDIM * 2) / 128), b1(256);
  gemm_bn_f16_kernel<<<g1, b1, 0, stream>>>(x, W, gamma, beta, rmean, rvar, out, wzp);
  rnn_sync_kernel<<<dim3(128), dim3(512), 0, stream>>>(U, out, wzp, xbuf);
}